// Round 1
// baseline (225.324 us; speedup 1.0000x reference)
//
#include <hip/hip_runtime.h>
#include <cstdint>

// Problem: y = clip(round((x @ W^T) * (sx*sw/sy)), -128, 127)
// M = 4*2048 = 8192, N = 4096, K = 4096.
// Inputs arrive as int32 (harness widens integer dtypes): pack to int8 in d_ws,
// then m97-structure MFMA i8 GEMM (128x128 tile, BK=64, global_load_lds w=16).

#define MDIM 8192
#define NDIM 4096
#define KDIM 4096
#define BM 128
#define BN 128
#define BK 64

typedef int v4i __attribute__((ext_vector_type(4)));

__device__ __forceinline__ uint32_t pack4(int a, int b, int c, int d) {
  return (uint32_t)(a & 0xFF) | ((uint32_t)(b & 0xFF) << 8) |
         ((uint32_t)(c & 0xFF) << 16) | ((uint32_t)(d & 0xFF) << 24);
}

// ---------- pre-pass: int32 -> int8 pack (memory-bound) + scale_y tail copy ----
__global__ __launch_bounds__(256) void pack_kernel(
    const int* __restrict__ x32, const int* __restrict__ w32,
    const float* __restrict__ sy, uint8_t* __restrict__ x8,
    uint8_t* __restrict__ w8, float* __restrict__ tail) {
  size_t idx = (size_t)blockIdx.x * blockDim.x + threadIdx.x;
  if (idx < (size_t)NDIM) tail[idx] = sy[idx];  // scale_y passthrough (output 1)
  const size_t NX = (size_t)MDIM * KDIM;  // 33554432
  const size_t NW = (size_t)NDIM * KDIM;  // 16777216
  size_t base = idx * 16;
  const int* src;
  uint8_t* dst;
  if (base < NX) {
    src = x32 + base;
    dst = x8 + base;
  } else if (base < NX + NW) {
    src = w32 + (base - NX);
    dst = w8 + (base - NX);
  } else {
    return;
  }
  v4i a0 = *(const v4i*)(src + 0);
  v4i a1 = *(const v4i*)(src + 4);
  v4i a2 = *(const v4i*)(src + 8);
  v4i a3 = *(const v4i*)(src + 12);
  v4i o;
  o[0] = (int)pack4(a0[0], a0[1], a0[2], a0[3]);
  o[1] = (int)pack4(a1[0], a1[1], a1[2], a1[3]);
  o[2] = (int)pack4(a2[0], a2[1], a2[2], a2[3]);
  o[3] = (int)pack4(a3[0], a3[1], a3[2], a3[3]);
  *(v4i*)dst = o;
}

__global__ __launch_bounds__(256) void tail_kernel(const float* __restrict__ sy,
                                                   float* __restrict__ tail) {
  int i = blockIdx.x * blockDim.x + threadIdx.x;
  if (i < NDIM) tail[i] = sy[i];
}

// ---------- main GEMM: m97 structure, int8 MFMA -------------------------------
// PACKED=1: stage from int8 buffers via global_load_lds (width 16).
// PACKED=0: fallback (ws too small): load int32, pack in regs, ds_write_b128.
template <int PACKED>
__global__ __launch_bounds__(256) void gemm_kernel(
    const uint8_t* __restrict__ A8, const uint8_t* __restrict__ B8,
    const int* __restrict__ A32, const int* __restrict__ B32,
    const float* __restrict__ sxp, const float* __restrict__ swp,
    const float* __restrict__ syp, float* __restrict__ out) {
  __shared__ __align__(16) uint8_t As[BM][BK];  // 8 KB
  __shared__ __align__(16) uint8_t Bs[BN][BK];  // 8 KB

  const int tid = threadIdx.x;
  const int lane = tid & 63;
  const int wave = tid >> 6;

  // XCD-aware swizzle (nwg = 2048, divisible by 8 -> bijective)
  const int nwg = (MDIM / BM) * (NDIM / BN);
  const int cpx = nwg / 8;
  int orig = blockIdx.x;
  int wg = (orig % 8) * cpx + orig / 8;
  const int ntn = NDIM / BN;  // 32
  int tm = wg / ntn, tn = wg % ntn;
  const int rowBase = tm * BM, colBase = tn * BN;

  // 2x2 wave grid, 64x64 output per wave
  const int wm = (wave >> 1) * 64;
  const int wn = (wave & 1) * 64;

  // staging map: thread -> (row = wave*16 + lane/4, 16B chunk = lane%4)
  const int srow = wave * 16 + (lane >> 2);
  const int scol = (lane & 3) * 16;

  // fragment map for mfma_i32_16x16x64_i8: lane holds 16 consecutive K-bytes
  const int kl = lane >> 4;  // k-chunk group (0..3) -> k = kl*16..kl*16+15
  const int fr = lane & 15;  // row (A) / col (B) within 16x16 fragment

  v4i acc[4][4];
#pragma unroll
  for (int i = 0; i < 4; i++)
#pragma unroll
    for (int j = 0; j < 4; j++) acc[i][j] = (v4i){0, 0, 0, 0};

  for (int kt = 0; kt < KDIM; kt += BK) {
    if (PACKED) {
      const uint8_t* ag = A8 + (size_t)(rowBase + srow) * KDIM + kt + scol;
      const uint8_t* bg = B8 + (size_t)(colBase + srow) * KDIM + kt + scol;
      __builtin_amdgcn_global_load_lds(
          (const __attribute__((address_space(1))) void*)ag,
          (__attribute__((address_space(3))) void*)(&As[srow][scol]), 16, 0, 0);
      __builtin_amdgcn_global_load_lds(
          (const __attribute__((address_space(1))) void*)(ag + (size_t)64 * KDIM),
          (__attribute__((address_space(3))) void*)(&As[64 + srow][scol]), 16, 0, 0);
      __builtin_amdgcn_global_load_lds(
          (const __attribute__((address_space(1))) void*)bg,
          (__attribute__((address_space(3))) void*)(&Bs[srow][scol]), 16, 0, 0);
      __builtin_amdgcn_global_load_lds(
          (const __attribute__((address_space(1))) void*)(bg + (size_t)64 * KDIM),
          (__attribute__((address_space(3))) void*)(&Bs[64 + srow][scol]), 16, 0, 0);
    } else {
#pragma unroll
      for (int c = 0; c < 2; ++c) {
        const int* ag = A32 + (size_t)(rowBase + c * 64 + srow) * KDIM + kt + scol;
        v4i p0 = *(const v4i*)(ag + 0), p1 = *(const v4i*)(ag + 4);
        v4i p2 = *(const v4i*)(ag + 8), p3 = *(const v4i*)(ag + 12);
        v4i oa;
        oa[0] = (int)pack4(p0[0], p0[1], p0[2], p0[3]);
        oa[1] = (int)pack4(p1[0], p1[1], p1[2], p1[3]);
        oa[2] = (int)pack4(p2[0], p2[1], p2[2], p2[3]);
        oa[3] = (int)pack4(p3[0], p3[1], p3[2], p3[3]);
        *(v4i*)&As[c * 64 + srow][scol] = oa;
        const int* bgp = B32 + (size_t)(colBase + c * 64 + srow) * KDIM + kt + scol;
        v4i q0 = *(const v4i*)(bgp + 0), q1 = *(const v4i*)(bgp + 4);
        v4i q2 = *(const v4i*)(bgp + 8), q3 = *(const v4i*)(bgp + 12);
        v4i ob;
        ob[0] = (int)pack4(q0[0], q0[1], q0[2], q0[3]);
        ob[1] = (int)pack4(q1[0], q1[1], q1[2], q1[3]);
        ob[2] = (int)pack4(q2[0], q2[1], q2[2], q2[3]);
        ob[3] = (int)pack4(q3[0], q3[1], q3[2], q3[3]);
        *(v4i*)&Bs[c * 64 + srow][scol] = ob;
      }
    }
    __syncthreads();

    v4i af[4], bf[4];
#pragma unroll
    for (int i = 0; i < 4; i++)
      af[i] = *(const v4i*)&As[wm + i * 16 + fr][kl * 16];
#pragma unroll
    for (int j = 0; j < 4; j++)
      bf[j] = *(const v4i*)&Bs[wn + j * 16 + fr][kl * 16];
#pragma unroll
    for (int i = 0; i < 4; i++)
#pragma unroll
      for (int j = 0; j < 4; j++)
        acc[i][j] =
            __builtin_amdgcn_mfma_i32_16x16x64_i8(af[i], bf[j], acc[i][j], 0, 0, 0);
    __syncthreads();
  }

  // epilogue: requantize, round-half-even, clip, store as float
  const float s = sxp[0] * swp[0];
#pragma unroll
  for (int j = 0; j < 4; j++) {
    const int col = colBase + wn + j * 16 + fr;
    const float rs = s / syp[col];
#pragma unroll
    for (int i = 0; i < 4; i++) {
      const int row0 = rowBase + wm + i * 16 + kl * 4;
#pragma unroll
      for (int r = 0; r < 4; r++) {
        float v = rintf((float)acc[i][j][r] * rs);
        v = fminf(127.f, fmaxf(-128.f, v));
        out[(size_t)(row0 + r) * NDIM + col] = v;
      }
    }
  }
}

extern "C" void kernel_launch(void* const* d_in, const int* in_sizes, int n_in,
                              void* d_out, int out_size, void* d_ws, size_t ws_size,
                              hipStream_t stream) {
  const int* x32 = (const int*)d_in[0];
  const int* w32 = (const int*)d_in[1];
  const float* sx = (const float*)d_in[2];
  const float* sw = (const float*)d_in[3];
  const float* sy = (const float*)d_in[4];
  float* out = (float*)d_out;
  float* tail = out + (size_t)MDIM * NDIM;  // scale_y appended after out_q

  const size_t need = (size_t)MDIM * KDIM + (size_t)NDIM * KDIM;  // 50.3 MB
  const int nblocks_gemm = (MDIM / BM) * (NDIM / BN);             // 2048

  if (ws_size >= need) {
    uint8_t* x8 = (uint8_t*)d_ws;
    uint8_t* w8 = x8 + (size_t)MDIM * KDIM;
    const int total16 = (int)(need / 16);  // 3,145,728 threads
    pack_kernel<<<(total16 + 255) / 256, 256, 0, stream>>>(x32, w32, sy, x8, w8,
                                                           tail);
    gemm_kernel<1><<<nblocks_gemm, 256, 0, stream>>>(x8, w8, nullptr, nullptr, sx,
                                                     sw, sy, out);
  } else {
    tail_kernel<<<(NDIM + 255) / 256, 256, 0, stream>>>(sy, tail);
    gemm_kernel<0><<<nblocks_gemm, 256, 0, stream>>>(nullptr, nullptr, x32, w32,
                                                     sx, sw, sy, out);
  }
}

// Round 2
// 194.977 us; speedup vs baseline: 1.1556x; 1.1556x over previous
//
#include <hip/hip_runtime.h>
#include <cstdint>

// y = clip(round((x @ W^T) * (sx*sw/sy)), -128, 127), M=8192 N=4096 K=4096 int8.
// Pass 1: int32 -> int8 pack into d_ws (memory-bound).
// Pass 2: 256x256-tile i8 MFMA GEMM, ring-4 LDS pipeline (BK=64B), counted
//         vmcnt(4) (never 0 in main loop), XOR-swizzled LDS (T2), XCD swizzle (T1).

#define MDIM 8192
#define NDIM 4096
#define KDIM 4096
#define BM 256
#define BN 256
#define BKB 64            // K-bytes (= int8 elements) per tile
#define NT (KDIM / BKB)   // 64 K-tiles

typedef int v4i __attribute__((ext_vector_type(4)));

#define FENCE() asm volatile("" ::: "memory")
#define BAR()                         \
  do {                                \
    FENCE();                          \
    __builtin_amdgcn_s_barrier();     \
    FENCE();                          \
  } while (0)

__device__ __forceinline__ uint32_t pack4(int a, int b, int c, int d) {
  return (uint32_t)(a & 0xFF) | ((uint32_t)(b & 0xFF) << 8) |
         ((uint32_t)(c & 0xFF) << 16) | ((uint32_t)(d & 0xFF) << 24);
}

// ---------- pre-pass: int32 -> int8 pack + scale_y tail copy ------------------
__global__ __launch_bounds__(256) void pack_kernel(
    const int* __restrict__ x32, const int* __restrict__ w32,
    const float* __restrict__ sy, uint8_t* __restrict__ x8,
    uint8_t* __restrict__ w8, float* __restrict__ tail) {
  size_t idx = (size_t)blockIdx.x * blockDim.x + threadIdx.x;
  if (idx < (size_t)NDIM) tail[idx] = sy[idx];
  const size_t NX = (size_t)MDIM * KDIM;
  const size_t NW = (size_t)NDIM * KDIM;
  size_t base = idx * 16;
  const int* src;
  uint8_t* dst;
  if (base < NX) {
    src = x32 + base;
    dst = x8 + base;
  } else if (base < NX + NW) {
    src = w32 + (base - NX);
    dst = w8 + (base - NX);
  } else {
    return;
  }
  v4i a0 = *(const v4i*)(src + 0);
  v4i a1 = *(const v4i*)(src + 4);
  v4i a2 = *(const v4i*)(src + 8);
  v4i a3 = *(const v4i*)(src + 12);
  v4i o;
  o[0] = (int)pack4(a0[0], a0[1], a0[2], a0[3]);
  o[1] = (int)pack4(a1[0], a1[1], a1[2], a1[3]);
  o[2] = (int)pack4(a2[0], a2[1], a2[2], a2[3]);
  o[3] = (int)pack4(a3[0], a3[1], a3[2], a3[3]);
  *(v4i*)dst = o;
}

// ---------- main GEMM ----------------------------------------------------------
// 512 threads = 8 waves (2M x 4N), per-wave output 128x64.
// LDS ring: A bufs lds[buf*16384 .. +16K), B bufs lds[65536 + buf*16384 .. +16K),
// buf = t & 3. Tile layout [256 rows][64 B], 16B slot swizzle: slot ^= (row & 3).
__global__ __launch_bounds__(512, 2) void gemm_kernel(
    const uint8_t* __restrict__ A8, const uint8_t* __restrict__ B8,
    const float* __restrict__ sxp, const float* __restrict__ swp,
    const float* __restrict__ syp, float* __restrict__ out) {
  __shared__ __align__(16) uint8_t lds[131072];

  const int tid = threadIdx.x;
  const int lane = tid & 63;
  const int wave = tid >> 6;

  // XCD-aware swizzle (nwg = 512, divisible by 8 -> bijective)
  const int nwg = (MDIM / BM) * (NDIM / BN);  // 512
  const int cpx = nwg / 8;
  const int wg = ((int)blockIdx.x % 8) * cpx + (int)blockIdx.x / 8;
  const int ntn = NDIM / BN;  // 16
  const int rowBase = (wg / ntn) * BM;
  const int colBase = (wg % ntn) * BN;

  const int wm2 = wave >> 2;  // 0..1 : M-half
  const int wn4 = wave & 3;   // 0..3 : N-quarter

  // ---- staging map: one gload round = 512 threads x 16 B = 128 rows ----------
  // LDS dest is linear (wave-uniform base + lane*16); the SOURCE column is
  // pre-swizzled so data lands where the swizzled reader expects it (rule #21).
  const int srow = wave * 16 + (lane >> 2);                      // + r*128
  const int scol = (((lane & 3) ^ ((lane >> 2) & 3)) << 4);      // swizzled src col
  const uint32_t sdst = (uint32_t)(wave * 1024 + lane * 16);     // + buf*16384 + r*8192

  // ---- fragment map (mfma_i32_16x16x64_i8): lane holds 16 consecutive K-bytes
  const int kl = lane >> 4;   // 16B k-slot 0..3
  const int fr = lane & 15;   // fragment row (A) / col (B)
  const int swz = ((kl ^ (fr & 3)) << 4);  // swizzled slot for this lane's rows

  uint32_t a_off[8], b_off[4];
#pragma unroll
  for (int i = 0; i < 8; i++)
    a_off[i] = (uint32_t)((wm2 * 128 + i * 16 + fr) * 64 + swz);
#pragma unroll
  for (int j = 0; j < 4; j++)
    b_off[j] = (uint32_t)(65536 + (wn4 * 64 + j * 16 + fr) * 64 + swz);

  v4i acc[8][4];
#pragma unroll
  for (int i = 0; i < 8; i++)
#pragma unroll
    for (int j = 0; j < 4; j++) acc[i][j] = (v4i){0, 0, 0, 0};

  auto stage = [&](int t) {
    const uint32_t ab = (uint32_t)(t & 3) * 16384u;
    const uint8_t* ga = A8 + (size_t)(rowBase + srow) * KDIM + t * BKB + scol;
    const uint8_t* gb = B8 + (size_t)(colBase + srow) * KDIM + t * BKB + scol;
    __builtin_amdgcn_global_load_lds(
        (const __attribute__((address_space(1))) void*)ga,
        (__attribute__((address_space(3))) void*)(lds + ab + sdst), 16, 0, 0);
    __builtin_amdgcn_global_load_lds(
        (const __attribute__((address_space(1))) void*)(ga + (size_t)128 * KDIM),
        (__attribute__((address_space(3))) void*)(lds + ab + 8192 + sdst), 16, 0, 0);
    __builtin_amdgcn_global_load_lds(
        (const __attribute__((address_space(1))) void*)gb,
        (__attribute__((address_space(3))) void*)(lds + 65536 + ab + sdst), 16, 0,
        0);
    __builtin_amdgcn_global_load_lds(
        (const __attribute__((address_space(1))) void*)(gb + (size_t)128 * KDIM),
        (__attribute__((address_space(3))) void*)(lds + 65536 + ab + 8192 + sdst),
        16, 0, 0);
  };

  // prologue: tiles 0 and 1 in flight (8 loads outstanding)
  stage(0);
  stage(1);

  for (int t = 0; t < NT; ++t) {
    // wait: oldest outstanding group (tile t's 4 loads) must be complete;
    // tile t+1's 4 loads stay in flight across the barrier (counted vmcnt, T4).
    if (t < NT - 1)
      asm volatile("s_waitcnt vmcnt(4)" ::: "memory");
    else
      asm volatile("s_waitcnt vmcnt(0)" ::: "memory");
    BAR();  // all waves' tile-t loads complete; also fences buf[t+2&3] reuse

    if (t + 2 < NT) stage(t + 2);  // prefetch 2 ahead into ring slot

    const uint8_t* Ab = lds + (uint32_t)(t & 3) * 16384u;
    v4i af[8], bf[4];
#pragma unroll
    for (int i = 0; i < 8; i++) af[i] = *(const v4i*)(Ab + a_off[i]);
#pragma unroll
    for (int j = 0; j < 4; j++) bf[j] = *(const v4i*)(Ab + b_off[j]);
#pragma unroll
    for (int i = 0; i < 8; i++)
#pragma unroll
      for (int j = 0; j < 4; j++)
        acc[i][j] =
            __builtin_amdgcn_mfma_i32_16x16x64_i8(af[i], bf[j], acc[i][j], 0, 0, 0);
  }

  // epilogue: requantize, round-half-even, clip, store float
  const float s = sxp[0] * swp[0];
  const int wrow = rowBase + wm2 * 128;
  const int wcol = colBase + wn4 * 64;
#pragma unroll
  for (int j = 0; j < 4; j++) {
    const int col = wcol + j * 16 + fr;
    const float rs = s / syp[col];
#pragma unroll
    for (int i = 0; i < 8; i++) {
      const int row0 = wrow + i * 16 + kl * 4;
#pragma unroll
      for (int r = 0; r < 4; r++) {
        float v = rintf((float)acc[i][j][r] * rs);
        v = fminf(127.f, fmaxf(-128.f, v));
        out[(size_t)(row0 + r) * NDIM + col] = v;
      }
    }
  }
}

extern "C" void kernel_launch(void* const* d_in, const int* in_sizes, int n_in,
                              void* d_out, int out_size, void* d_ws, size_t ws_size,
                              hipStream_t stream) {
  const int* x32 = (const int*)d_in[0];
  const int* w32 = (const int*)d_in[1];
  const float* sx = (const float*)d_in[2];
  const float* sw = (const float*)d_in[3];
  const float* sy = (const float*)d_in[4];
  float* out = (float*)d_out;
  float* tail = out + (size_t)MDIM * NDIM;

  uint8_t* x8 = (uint8_t*)d_ws;
  uint8_t* w8 = x8 + (size_t)MDIM * KDIM;
  const size_t need = (size_t)MDIM * KDIM + (size_t)NDIM * KDIM;  // ~50.3 MB
  (void)need;  // ws_size verified sufficient in round 1

  const int total16 = (int)(((size_t)MDIM * KDIM + (size_t)NDIM * KDIM) / 16);
  pack_kernel<<<(total16 + 255) / 256, 256, 0, stream>>>(x32, w32, sy, x8, w8,
                                                         tail);

  const int nblocks = (MDIM / BM) * (NDIM / BN);  // 512
  gemm_kernel<<<nblocks, 512, 0, stream>>>(x8, w8, sx, sw, sy, out);
}

// Round 3
// 182.182 us; speedup vs baseline: 1.2368x; 1.0702x over previous
//
#include <hip/hip_runtime.h>
#include <cstdint>

// y = clip(round((x @ W^T) * (sx*sw/sy)), -128, 127), M=8192 N=4096 K=4096 int8.
// Pass 1 (pack): int32 -> int8 AND permute into MFMA-fragment-major layout:
//   per (256-row-block, 128B-K-tile): 32KB block of 32 regions x 1KB;
//   region = rf*2 + kh (rf = 16-row fragment, kh = K-half); within region,
//   byte pos = lane*16 where lane = kl*16 + fr  (exact mfma_i32_16x16x64_i8
//   A/B operand order: lane holds rows fr, K-bytes kl*16..+15).
// Pass 2 (GEMM): staging = contiguous global_load_lds (linear src, linear dst);
//   fragment ds_read_b128 = region_base + lane*16 (stride-1, conflict-free).
//   Ring-2 LDS (2 x 64KB), counted vmcnt(8), 2 barriers per K-tile (BK=128).

#define MDIM 8192
#define NDIM 4096
#define KDIM 4096
#define BM 256
#define BN 256
#define BKB 128
#define NT (KDIM / BKB)      // 32 K-tiles
#define KTILES (KDIM / BKB)  // 32

typedef int v4i __attribute__((ext_vector_type(4)));

#define FENCE() asm volatile("" ::: "memory")
#define BAR()                     \
  do {                            \
    FENCE();                      \
    __builtin_amdgcn_s_barrier(); \
    FENCE();                      \
  } while (0)

__device__ __forceinline__ uint32_t pack4(int a, int b, int c, int d) {
  return (uint32_t)(a & 0xFF) | ((uint32_t)(b & 0xFF) << 8) |
         ((uint32_t)(c & 0xFF) << 16) | ((uint32_t)(d & 0xFF) << 24);
}

// ---------- pack: gather int32 -> fragment-major int8 + scale_y tail ----------
__global__ __launch_bounds__(256) void pack_kernel(
    const int* __restrict__ x32, const int* __restrict__ w32,
    const float* __restrict__ sy, uint8_t* __restrict__ x8f,
    uint8_t* __restrict__ w8f, float* __restrict__ tail) {
  const int t = blockIdx.x * 256 + threadIdx.x;
  if (t < NDIM) tail[t] = sy[t];
  const int NXC = (MDIM / 16) * KDIM;  // 2,097,152 16B-chunks for x
  const int NWC = (NDIM / 16) * KDIM;  // 1,048,576 for w
  if (t >= NXC + NWC) return;
  const int* src;
  uint8_t* dst;
  int chunk;
  if (t < NXC) {
    chunk = t;
    src = x32;
    dst = x8f;
  } else {
    chunk = t - NXC;
    src = w32;
    dst = w8f;
  }
  const int blk = chunk >> 11;  // 2048 chunks per 32KB block
  const int cb = chunk & 2047;
  const int mb = blk >> 5;   // row-block (256 rows)
  const int kt = blk & 31;   // K-tile (128 bytes)
  const int region = cb >> 6;
  const int lpos = cb & 63;
  const int rf = region >> 1, kh = region & 1;
  const int kl = lpos >> 4, fr = lpos & 15;
  const int r = mb * 256 + rf * 16 + fr;
  const int k0 = kt * 128 + kh * 64 + kl * 16;
  const int* s = src + (size_t)r * KDIM + k0;  // 16 int32 = 64B aligned line
  v4i a0 = *(const v4i*)(s + 0);
  v4i a1 = *(const v4i*)(s + 4);
  v4i a2 = *(const v4i*)(s + 8);
  v4i a3 = *(const v4i*)(s + 12);
  v4i o;
  o[0] = (int)pack4(a0[0], a0[1], a0[2], a0[3]);
  o[1] = (int)pack4(a1[0], a1[1], a1[2], a1[3]);
  o[2] = (int)pack4(a2[0], a2[1], a2[2], a2[3]);
  o[3] = (int)pack4(a3[0], a3[1], a3[2], a3[3]);
  *(v4i*)(dst + (size_t)chunk * 16) = o;  // linear, fully coalesced
}

// ---------- main GEMM ----------------------------------------------------------
// 512 threads = 8 waves (2M x 4N), per-wave output 128x64, acc 8x4 frags.
// LDS: [buf 0/1][A 32KB][B 32KB] = 128KB.
__global__ __launch_bounds__(512, 2) void gemm_kernel(
    const uint8_t* __restrict__ A8, const uint8_t* __restrict__ B8,
    const float* __restrict__ sxp, const float* __restrict__ swp,
    const float* __restrict__ syp, float* __restrict__ out) {
  __shared__ __align__(16) uint8_t lds[131072];

  const int tid = threadIdx.x;
  const int lane = tid & 63;
  const int wave = tid >> 6;

  // XCD-aware swizzle: nwg = 512 (divisible by 8 -> bijective)
  const int wg = ((int)blockIdx.x % 8) * 64 + (int)blockIdx.x / 8;
  const int mb = wg >> 4;  // 0..31
  const int nb = wg & 15;  // 0..15

  const int wm2 = wave >> 2;  // 0..1
  const int wn4 = wave & 3;   // 0..3

  const uint8_t* Abase = A8 + ((size_t)(mb * KTILES) << 15);
  const uint8_t* Bbase = B8 + ((size_t)(nb * KTILES) << 15);

  v4i acc[8][4];
#pragma unroll
  for (int i = 0; i < 8; i++)
#pragma unroll
    for (int j = 0; j < 4; j++) acc[i][j] = (v4i){0, 0, 0, 0};

  const uint32_t sdst = (uint32_t)tid * 16;  // wave-uniform base + lane*16

  auto stage = [&](int t) {
    const uint32_t lb = (uint32_t)(t & 1) * 65536u;
    const uint8_t* as = Abase + ((size_t)t << 15) + sdst;
    const uint8_t* bs = Bbase + ((size_t)t << 15) + sdst;
#pragma unroll
    for (int r = 0; r < 4; ++r) {
      __builtin_amdgcn_global_load_lds(
          (const __attribute__((address_space(1))) void*)(as + r * 8192),
          (__attribute__((address_space(3))) void*)(lds + lb + r * 8192 + sdst),
          16, 0, 0);
      __builtin_amdgcn_global_load_lds(
          (const __attribute__((address_space(1))) void*)(bs + r * 8192),
          (__attribute__((address_space(3))) void*)(lds + lb + 32768 + r * 8192 +
                                                    sdst),
          16, 0, 0);
    }
  };

  stage(0);  // 8 loads in flight

  for (int t = 0; t < NT; ++t) {
    if (t + 1 < NT) {
      stage(t + 1);  // 16 in flight; oldest 8 = tile t
      asm volatile("s_waitcnt vmcnt(8)" ::: "memory");
    } else {
      asm volatile("s_waitcnt vmcnt(0)" ::: "memory");
    }
    BAR();  // tile t visible to all waves

    const uint8_t* La = lds + (uint32_t)(t & 1) * 65536u;
    const uint8_t* Lb = La + 32768;
#pragma unroll
    for (int kh = 0; kh < 2; ++kh) {
      v4i af[8], bf[4];
#pragma unroll
      for (int i = 0; i < 8; i++)
        af[i] = *(const v4i*)(La + ((((wm2 * 8 + i) << 1) + kh) << 10) +
                              lane * 16);
#pragma unroll
      for (int j = 0; j < 4; j++)
        bf[j] = *(const v4i*)(Lb + ((((wn4 * 4 + j) << 1) + kh) << 10) +
                              lane * 16);
#pragma unroll
      for (int i = 0; i < 8; i++)
#pragma unroll
        for (int j = 0; j < 4; j++)
          acc[i][j] = __builtin_amdgcn_mfma_i32_16x16x64_i8(af[i], bf[j],
                                                            acc[i][j], 0, 0, 0);
    }
    BAR();  // all waves done reading buf[t&1] -> next iter may overwrite
  }

  // epilogue: requantize, round-half-even, clip, store float
  const float s = sxp[0] * swp[0];
  const int kl = lane >> 4;
  const int fr = lane & 15;
  const int wrow = mb * 256 + wm2 * 128;
  const int wcol = nb * 256 + wn4 * 64;
#pragma unroll
  for (int j = 0; j < 4; j++) {
    const int col = wcol + j * 16 + fr;
    const float rs = s / syp[col];
#pragma unroll
    for (int i = 0; i < 8; i++) {
      const int row0 = wrow + i * 16 + kl * 4;
#pragma unroll
      for (int r = 0; r < 4; r++) {
        float v = rintf((float)acc[i][j][r] * rs);
        v = fminf(127.f, fmaxf(-128.f, v));
        out[(size_t)(row0 + r) * NDIM + col] = v;
      }
    }
  }
}

extern "C" void kernel_launch(void* const* d_in, const int* in_sizes, int n_in,
                              void* d_out, int out_size, void* d_ws, size_t ws_size,
                              hipStream_t stream) {
  const int* x32 = (const int*)d_in[0];
  const int* w32 = (const int*)d_in[1];
  const float* sx = (const float*)d_in[2];
  const float* sw = (const float*)d_in[3];
  const float* sy = (const float*)d_in[4];
  float* out = (float*)d_out;
  float* tail = out + (size_t)MDIM * NDIM;

  uint8_t* x8f = (uint8_t*)d_ws;
  uint8_t* w8f = x8f + (size_t)MDIM * KDIM;

  const int total = (MDIM / 16) * KDIM + (NDIM / 16) * KDIM;  // 3,145,728
  pack_kernel<<<total / 256, 256, 0, stream>>>(x32, w32, sy, x8f, w8f, tail);

  const int nblocks = (MDIM / BM) * (NDIM / BN);  // 512
  gemm_kernel<<<nblocks, 512, 0, stream>>>(x8f, w8f, sx, sw, sy, out);
}